// Round 15
// baseline (158.689 us; speedup 1.0000x reference)
//
#include <hip/hip_runtime.h>
#include <hip/hip_bf16.h>

// Problem constants
#define NB 2
#define NI 384
#define NE 64
#define NH 8
#define NNI (NI*NI)                 // 147456
#define NROWS (NB*NNI)              // 294912
#define MCOLS (NI*8)                // 3072
#define PLANE ((size_t)NI*MCOLS)    // 1179648 elems per (b,h) Va plane
#define KPAD 416                    // padded K stride: rows = 832 B = 13 cache lines
                                    // (64B-aligned; payload 768 B = 12 full lines)
#define VPLANE_E ((size_t)MCOLS*KPAD)   // 1277952 elems per V plane
#define APLANE_E ((size_t)NI*KPAD)      // 159744 elems per A plane

typedef __attribute__((ext_vector_type(8))) short short8;
typedef __attribute__((ext_vector_type(4))) float floatx4;

struct alignas(8) US4 { unsigned short x, y, z, w; };

__device__ __forceinline__ float bf2f(unsigned short u){ return __uint_as_float(((unsigned)u) << 16); }
__device__ __forceinline__ unsigned short f2bf(float f){
    unsigned x = __float_as_uint(f);
    x += 0x7fffu + ((x >> 16) & 1u);          // round-to-nearest-even
    return (unsigned short)(x >> 16);
}

__device__ __forceinline__ float wave_sum(float v){
    #pragma unroll
    for (int m = 32; m > 0; m >>= 1) v += __shfl_xor(v, m, 64);
    return v;
}
__device__ __forceinline__ float wave_max(float v){
    #pragma unroll
    for (int m = 32; m > 0; m >>= 1) v = fmaxf(v, __shfl_xor(v, m, 64));
    return v;
}

// async global->LDS, 16B per lane; LDS dest is wave-uniform base + lane*16
__device__ __forceinline__ void gl_lds16(const unsigned short* g, unsigned short* l){
    __builtin_amdgcn_global_load_lds(
        (__attribute__((address_space(1))) void*)(g),
        (__attribute__((address_space(3))) void*)(l), 16, 0, 0);
}

// ---------------------------------------------------------------------------
// k_w: weight prep (unchanged from validated round-5 kernel).
// ---------------------------------------------------------------------------
__global__ __launch_bounds__(256) void k_w(
    const float* __restrict__ Wv, const float* __restrict__ Weg,
    const float* __restrict__ bV, const float* __restrict__ bEG,
    const float* __restrict__ Wo,
    unsigned short* __restrict__ WtA, unsigned short* __restrict__ WtB,
    float* __restrict__ bcoA, float* __restrict__ bcoB,
    unsigned short* __restrict__ WoT)
{
    const int t = threadIdx.x;
    for (int idx = t; idx < 5120; idx += 256){
        int n = idx >> 6, k = idx & 63;
        WtA[idx] = f2bf((n < 64) ? Wv[k*128 + n]      : Weg[k*32 + (n-64)]);
        WtB[idx] = f2bf((n < 64) ? Wv[k*128 + 64 + n] : Weg[k*32 + 16 + (n-64)]);
    }
    for (int idx = t; idx < 8192; idx += 256){
        int o = idx >> 7, c = idx & 127;
        int r = (c & 7)*16 + (c >> 3);
        WoT[idx] = f2bf(Wo[r*64 + o]);
    }
    if (t < 80){
        bcoA[t] = (t < 64) ? bV[t]      : bEG[t-64];
        bcoB[t] = (t < 64) ? bV[64 + t] : bEG[16 + t-64];
    }
}

// ---------------------------------------------------------------------------
// k_projsm (merged): fused LayerNorm + [384,64]@[64,80] bf16 MFMA projection
// + in-block gated softmax. R14-validated structure + ONE lever:
//  - S/G packed as bf16 pairs in u32 sgp[384][9] (13.5 KB, was 26.1 KB f32):
//    S-lane (lr<8) pulls partner G via __shfl_xor(.,8), packs. LDS total
//    40768 B -> exactly 4 blocks/CU (was 3). Safe now that KPAD=416 makes
//    every V-plane line whole-written by one wave (R12's write blowup was
//    the unaligned-row partial-line effect, fixed in R13/R14).
// ---------------------------------------------------------------------------
__global__ __launch_bounds__(256, 4) void k_projsm(
    const float* __restrict__ e, const float* __restrict__ lns, const float* __restrict__ lnb,
    const unsigned short* __restrict__ WtA, const unsigned short* __restrict__ WtB,
    const float* __restrict__ bcoA, const float* __restrict__ bcoB,
    const float* __restrict__ mask,
    unsigned short* __restrict__ VinP, unsigned short* __restrict__ VoutP,
    unsigned short* __restrict__ AinP, unsigned short* __restrict__ AoutP)
{
    __shared__ unsigned short Alds[128*64];   // 16 KB, XOR-swizzled chunks
    __shared__ unsigned short Wlds[80*64];    // 10 KB, XOR-swizzled chunks
    __shared__ float bcs[80];                 // 320 B
    __shared__ unsigned sgp[384][9];          // 13.5 KB: lo16=S bf16, hi16=G bf16
    const int tid = threadIdx.x;
    const int y    = blockIdx.x;
    const int b    = blockIdx.y;
    const int pass = blockIdx.z;
    const int z8 = b * 8;

    const unsigned short* Wt = pass ? WtB : WtA;
    const float* bco         = pass ? bcoB : bcoA;
    unsigned short* Vdst     = pass ? VoutP : VinP;
    unsigned short* Adst     = pass ? AoutP : AinP;

    // stage weight slice into swizzled LDS [80][64]
    for (int c = tid; c < 640; c += 256){
        int n = c >> 3, pos = (c & 7) ^ (n & 7);
        short8 v = *(const short8*)&Wt[c*8];
        *(short8*)&Wlds[n*64 + pos*8] = v;
    }
    if (tid < 80) bcs[tid] = bco[tid];

    const int lq = tid & 3;
    float scv[16], bsv[16];
    #pragma unroll
    for (int j = 0; j < 4; ++j){
        float4 s4 = *(const float4*)&lns[lq*16 + j*4];
        float4 b4 = *(const float4*)&lnb[lq*16 + j*4];
        scv[j*4+0]=s4.x; scv[j*4+1]=s4.y; scv[j*4+2]=s4.z; scv[j*4+3]=s4.w;
        bsv[j*4+0]=b4.x; bsv[j*4+1]=b4.y; bsv[j*4+2]=b4.z; bsv[j*4+3]=b4.w;
    }

    const int w = tid >> 6, l = tid & 63;
    const int lr = l & 15, lk4 = l >> 4;
    const int rowoff = lk4 * 4;

    auto LOAD = [&](float (&xs)[2][16], int cx){
        #pragma unroll
        for (int p = 0; p < 2; ++p){
            int lrow = p*64 + (tid >> 2);
            size_t gbase;
            if (pass == 0) gbase = (((size_t)(b*NI + y)) * NI + cx*128 + lrow) * NE + lq*16;
            else           gbase = (((size_t)(b*NI + cx*128 + lrow)) * NI + y) * NE + lq*16;
            #pragma unroll
            for (int j = 0; j < 4; ++j){
                float4 x4 = *(const float4*)&e[gbase + j*4];
                xs[p][j*4+0]=x4.x; xs[p][j*4+1]=x4.y; xs[p][j*4+2]=x4.z; xs[p][j*4+3]=x4.w;
            }
        }
    };

    auto LNWRITE = [&](const float (&xs)[2][16]){
        #pragma unroll
        for (int p = 0; p < 2; ++p){
            int lrow = p*64 + (tid >> 2);
            float s = 0.f, sq = 0.f;
            #pragma unroll
            for (int j = 0; j < 16; ++j){ s += xs[p][j]; sq += xs[p][j]*xs[p][j]; }
            s  += __shfl_xor(s, 1, 64);  s  += __shfl_xor(s, 2, 64);
            sq += __shfl_xor(sq, 1, 64); sq += __shfl_xor(sq, 2, 64);
            float mu = s * (1.f/64.f);
            float var = sq * (1.f/64.f) - mu*mu;
            float rs = rsqrtf(var + 1e-5f);
            short8 o0, o1;
            #pragma unroll
            for (int j = 0; j < 8; ++j){
                o0[j] = (short)f2bf((xs[p][j]   - mu)*rs*scv[j]   + bsv[j]);
                o1[j] = (short)f2bf((xs[p][j+8] - mu)*rs*scv[j+8] + bsv[j+8]);
            }
            const int sw = lrow & 7;
            *(short8*)&Alds[lrow*64 + ((lq*2    ) ^ sw)*8] = o0;
            *(short8*)&Alds[lrow*64 + ((lq*2 + 1) ^ sw)*8] = o1;
        }
    };

    float xsA[2][16], xsB[2][16];
    LOAD(xsA, 0);

    #pragma unroll
    for (int cx = 0; cx < 3; ++cx){
        const int x0 = cx * 128;
        __syncthreads();   // Wlds staged (cx=0) / prev chunk's Alds reads done
        if (cx & 1) LNWRITE(xsB); else LNWRITE(xsA);
        __syncthreads();   // Alds ready
        if (cx == 0) LOAD(xsB, 1);           // prefetch: hides under MFMA+epilogue
        else if (cx == 1) LOAD(xsA, 2);

        // MFMA: wave w owns rows w*32..w*32+31 (2 frags) x 80 cols (5 frags)
        floatx4 acc[2][5];
        #pragma unroll
        for (int mf = 0; mf < 2; ++mf)
            #pragma unroll
            for (int nf = 0; nf < 5; ++nf)
                acc[mf][nf] = (floatx4){0.f,0.f,0.f,0.f};

        #pragma unroll
        for (int ks = 0; ks < 2; ++ks){
            const int ch = ((ks*4 + lk4) ^ (lr & 7)) * 8;
            short8 a0 = *(const short8*)&Alds[(w*32 +  0 + lr)*64 + ch];
            short8 a1 = *(const short8*)&Alds[(w*32 + 16 + lr)*64 + ch];
            #pragma unroll
            for (int nf = 0; nf < 5; ++nf){
                short8 bfr = *(const short8*)&Wlds[(nf*16 + lr)*64 + ch];
                acc[0][nf] = __builtin_amdgcn_mfma_f32_16x16x32_bf16(a0, bfr, acc[0][nf], 0, 0, 0);
                acc[1][nf] = __builtin_amdgcn_mfma_f32_16x16x32_bf16(a1, bfr, acc[1][nf], 0, 0, 0);
            }
        }

        // Epilogue: V columns -> coalesced global; S/G columns -> packed LDS
        #pragma unroll
        for (int mf = 0; mf < 2; ++mf){
            const int bl = x0 + w*32 + mf*16 + rowoff;
            #pragma unroll
            for (int nf = 0; nf < 4; ++nf){
                int ca = nf*16 + lr;
                int dd = ca >> 3, h = ca & 7;
                float bia = bcs[ca];
                US4 v;
                v.x = f2bf(acc[mf][nf][0] + bia);
                v.y = f2bf(acc[mf][nf][1] + bia);
                v.z = f2bf(acc[mf][nf][2] + bia);
                v.w = f2bf(acc[mf][nf][3] + bia);
                *(US4*)&Vdst[(size_t)(z8 + h)*VPLANE_E + (size_t)(y*8 + dd)*KPAD + bl] = v;
            }
            {
                // lanes lr<8 hold S (cols 64..71); lanes lr>=8 hold G (72..79).
                // lane l ^ 8 is the partner with the same lk4 / bl.
                float bia = bcs[64 + lr];
                #pragma unroll
                for (int q = 0; q < 4; ++q){
                    float v = acc[mf][4][q] + bia;
                    float o = __shfl_xor(v, 8, 64);     // partner value
                    if (lr < 8){
                        unsigned pk = ((unsigned)f2bf(v)) | (((unsigned)f2bf(o)) << 16);
                        sgp[bl + q][lr] = pk;           // lo=S, hi=G
                    }
                }
            }
        }
    }
    __syncthreads();

    // Softmax + gate over the block's 384-row axis; wave w owns h = 2w, 2w+1
    float mv[6];
    if (pass == 0){
        #pragma unroll
        for (int q = 0; q < 6; ++q)
            mv[q] = mask[((size_t)b*NI + y)*NI + l + q*64];
    }
    #pragma unroll
    for (int hh = 0; hh < 2; ++hh){
        const int h = w*2 + hh;
        float sv[6], gv[6];
        float m = -1e30f;
        #pragma unroll
        for (int q = 0; q < 6; ++q){
            int j = l + q*64;
            unsigned pk = sgp[j][h];
            float mk = (pass == 0) ? mv[q] : 0.f;
            sv[q] = bf2f((unsigned short)(pk & 0xffffu)) + mk;
            gv[q] = bf2f((unsigned short)(pk >> 16))     + mk;
            m = fmaxf(m, sv[q]);
        }
        m = wave_max(m);
        float ssum = 0.f;
        #pragma unroll
        for (int q = 0; q < 6; ++q){ sv[q] = expf(sv[q] - m); ssum += sv[q]; }
        ssum = wave_sum(ssum);
        float inv = 1.f / ssum;
        unsigned short* dst = Adst + (size_t)(z8 + h)*APLANE_E + (size_t)y*KPAD;
        #pragma unroll
        for (int q = 0; q < 6; ++q){
            float sig = 1.f / (1.f + expf(-gv[q]));
            dst[l + q*64] = f2bf(sv[q] * inv * sig);
        }
    }
}

// ---------------------------------------------------------------------------
// k_gemm: C[384,3072] = A[384,384] @ B^T (B stored [n][k]), bf16 MFMA.
// (unchanged validated round-7 kernel: 0 bank conflicts)
// ---------------------------------------------------------------------------
__global__ __launch_bounds__(256, 2) void k_gemm(
    const unsigned short* __restrict__ AinP, const unsigned short* __restrict__ AoutP,
    const unsigned short* __restrict__ VinP, const unsigned short* __restrict__ VoutP,
    unsigned short* __restrict__ VaIn, unsigned short* __restrict__ VaOut)
{
    __shared__ unsigned short Al[128*64];    // 16 KB, linear [row][64], swizzled chunks
    __shared__ unsigned short Bl[256*64];    // 32 KB
    const int tid = threadIdx.x;

    // XCD-aware bijective swizzle: 1152 blocks = 8 XCDs x 144
    const int L = blockIdx.x;
    const int W = (L & 7) * 144 + (L >> 3);
    const int nt = W % 12;
    const int mt = (W / 12) % 3;
    const int z  = W / 36;
    const int dir = z >> 4, bh = z & 15;
    const unsigned short* Ap = (dir ? AoutP : AinP) + (size_t)bh * APLANE_E;
    const unsigned short* Bp = (dir ? VoutP : VinP) + (size_t)bh * VPLANE_E;
    unsigned short* Cp = (dir ? VaOut : VaIn) + (size_t)bh * PLANE;
    const int m0 = mt*128, n0 = nt*256;

    const int w = tid >> 6, l = tid & 63;
    const int lr = l & 15, lk4 = l >> 4;
    const int wr = w >> 1, wc = w & 1;

    // staging lane geometry: lane l covers (row_in_inst = l>>3, physical chunk = l&7)
    const int srow8  = l >> 3;                      // 0..7
    const int schunk = (l & 7) ^ (srow8 & 7);       // logical chunk to fetch

    floatx4 acc[4][8];
    #pragma unroll
    for (int mf = 0; mf < 4; ++mf)
        #pragma unroll
        for (int nf = 0; nf < 8; ++nf)
            acc[mf][nf] = (floatx4){0.f,0.f,0.f,0.f};

    for (int kb = 0; kb < 6; ++kb){
        const int k0 = kb*64;
        __syncthreads();                            // prev compute done before overwrite
        #pragma unroll
        for (int t = 0; t < 4; ++t){
            int inst = w*4 + t;
            gl_lds16(&Ap[(size_t)(m0 + inst*8 + srow8)*KPAD + k0 + schunk*8],
                     &Al[inst*512]);
        }
        #pragma unroll
        for (int t = 0; t < 8; ++t){
            int inst = w*8 + t;
            gl_lds16(&Bp[(size_t)(n0 + inst*8 + srow8)*KPAD + k0 + schunk*8],
                     &Bl[inst*512]);
        }
        asm volatile("s_waitcnt vmcnt(0)" ::: "memory");
        __syncthreads();
        #pragma unroll
        for (int ks = 0; ks < 2; ++ks){
            const int cx = ((ks*4 + lk4) ^ (lr & 7)) * 8;   // swizzled chunk offset (shorts)
            short8 a[4], b[8];
            #pragma unroll
            for (int mf = 0; mf < 4; ++mf)
                a[mf] = *(const short8*)&Al[(wr*64 + mf*16 + lr)*64 + cx];
            #pragma unroll
            for (int nf = 0; nf < 8; ++nf)
                b[nf] = *(const short8*)&Bl[(wc*128 + nf*16 + lr)*64 + cx];
            #pragma unroll
            for (int mf = 0; mf < 4; ++mf)
                #pragma unroll
                for (int nf = 0; nf < 8; ++nf)
                    acc[mf][nf] = __builtin_amdgcn_mfma_f32_16x16x32_bf16(a[mf], b[nf], acc[mf][nf], 0, 0, 0);
        }
    }

    const int rowoff = lk4 * 4;
    #pragma unroll
    for (int mf = 0; mf < 4; ++mf)
        #pragma unroll
        for (int q = 0; q < 4; ++q){
            int i = m0 + wr*64 + mf*16 + rowoff + q;
            #pragma unroll
            for (int nf = 0; nf < 8; ++nf){
                int n = n0 + wc*128 + nf*16 + lr;
                Cp[(size_t)i*MCOLS + n] = f2bf(acc[mf][nf][q]);
            }
        }
}

// ---------------------------------------------------------------------------
// k_f2: epilogue GEMM via MFMA, no A-staging.
// (unchanged from validated round-5 kernel)
// ---------------------------------------------------------------------------
__global__ __launch_bounds__(192) void k_f2(
    const unsigned short* __restrict__ Vain, const unsigned short* __restrict__ Vaout,
    const unsigned short* __restrict__ WoT, const float* __restrict__ bO,
    float* __restrict__ out)
{
    __shared__ unsigned short wl[64*136];
    const int tid = threadIdx.x;
    const int jt = blockIdx.x, i = blockIdx.y, b = blockIdx.z;

    for (int cc = tid; cc < 1024; cc += 192){     // stage WoT [64][128] -> [64][136]
        int o = cc >> 4, k8 = (cc & 15) * 8;
        short8 v = *(const short8*)&WoT[cc*8];
        *(short8*)&wl[o*136 + k8] = v;
    }

    const int w = tid >> 6, l = tid & 63;
    const int lr = l & 15, lk = (l >> 4) * 8;
    const int j0 = jt*192 + w*64;

    float bias[4];
    #pragma unroll
    for (int nf = 0; nf < 4; ++nf) bias[nf] = bO[nf*16 + lr];

    __syncthreads();

    short8 bfr[4][4];
    #pragma unroll
    for (int ks = 0; ks < 4; ++ks)
        #pragma unroll
        for (int nf = 0; nf < 4; ++nf)
            bfr[ks][nf] = *(const short8*)&wl[(nf*16 + lr)*136 + ks*32 + lk];

    floatx4 acc[4][4];
    #pragma unroll
    for (int mf = 0; mf < 4; ++mf)
        #pragma unroll
        for (int nf = 0; nf < 4; ++nf)
            acc[mf][nf] = (floatx4){0.f,0.f,0.f,0.f};

    const int p_lane = (l >> 4);
    #pragma unroll
    for (int mf = 0; mf < 4; ++mf){
        int j = j0 + mf*16 + lr;
        short8 a[4];
        #pragma unroll
        for (int ks = 0; ks < 4; ++ks){
            int p = ks*4 + p_lane;
            const unsigned short* src = (p >= 8) ? Vaout : Vain;
            int h = p & 7;
            a[ks] = *(const short8*)&src[(size_t)(b*8 + h)*PLANE + (size_t)i*MCOLS + (size_t)j*8];
        }
        #pragma unroll
        for (int ks = 0; ks < 4; ++ks)
            #pragma unroll
            for (int nf = 0; nf < 4; ++nf)
                acc[mf][nf] = __builtin_amdgcn_mfma_f32_16x16x32_bf16(a[ks], bfr[ks][nf], acc[mf][nf], 0, 0, 0);
    }

    const int rowoff = (l >> 4) * 4;
    const size_t obase = ((size_t)(b*NI + i)) * NI;
    #pragma unroll
    for (int mf = 0; mf < 4; ++mf)
        #pragma unroll
        for (int q = 0; q < 4; ++q){
            int j = j0 + mf*16 + rowoff + q;
            #pragma unroll
            for (int nf = 0; nf < 4; ++nf)
                out[(obase + j)*NE + nf*16 + lr] = acc[mf][nf][q] + bias[nf];
        }
}

// ---------------------------------------------------------------------------
extern "C" void kernel_launch(void* const* d_in, const int* in_sizes, int n_in,
                              void* d_out, int out_size, void* d_ws, size_t ws_size,
                              hipStream_t stream)
{
    const float* e    = (const float*)d_in[0];
    const float* mask = (const float*)d_in[1];
    const float* lns  = (const float*)d_in[2];
    const float* lnb  = (const float*)d_in[3];
    const float* Wv   = (const float*)d_in[4];
    const float* bV   = (const float*)d_in[5];
    const float* Weg  = (const float*)d_in[6];
    const float* bEG  = (const float*)d_in[7];
    const float* Wo   = (const float*)d_in[8];
    const float* bO   = (const float*)d_in[9];

    // ws layout (bytes): VinP/VoutP 2x40,894,464 (ends 81,788,928) |
    // AinP/AoutP 2x5,111,808 (ends 92,012,544) | weights ~37.5 KB (ends
    // 92,050,048) | VaIn+VaOut 2x37,748,736 (ends 167,547,520) < 188,743,680
    unsigned short* VinP  = (unsigned short*)d_ws;
    unsigned short* VoutP = VinP  + (size_t)16 * VPLANE_E;
    unsigned short* AinP  = VoutP + (size_t)16 * VPLANE_E;
    unsigned short* AoutP = AinP  + (size_t)16 * APLANE_E;
    unsigned short* WtA   = AoutP + (size_t)16 * APLANE_E;
    unsigned short* WtB   = WtA + 5120;
    unsigned short* WoT   = WtB + 5120;
    float* bcoA = (float*)(WoT + 8192);
    float* bcoB = bcoA + 80;
    unsigned short* VaIn  = (unsigned short*)(bcoB + 80);
    unsigned short* VaOut = VaIn + (size_t)16 * PLANE;

    k_w<<<1, 256, 0, stream>>>(Wv, Weg, bV, bEG, Wo, WtA, WtB, bcoA, bcoB, WoT);
    k_projsm<<<dim3(NI, NB, 2), 256, 0, stream>>>(e, lns, lnb, WtA, WtB, bcoA, bcoB,
                                                  mask, VinP, VoutP, AinP, AoutP);
    k_gemm<<<dim3(1152), 256, 0, stream>>>(AinP, AoutP, VinP, VoutP, VaIn, VaOut);
    k_f2  <<<dim3(2, NI, NB), 192, 0, stream>>>(VaIn, VaOut, WoT, bO, (float*)d_out);
}

// Round 16
// 150.616 us; speedup vs baseline: 1.0536x; 1.0536x over previous
//
#include <hip/hip_runtime.h>
#include <hip/hip_bf16.h>

// Problem constants
#define NB 2
#define NI 384
#define NE 64
#define NH 8
#define NNI (NI*NI)                 // 147456
#define NROWS (NB*NNI)              // 294912
#define MCOLS (NI*8)                // 3072
#define PLANE ((size_t)NI*MCOLS)    // 1179648 elems per (b,h) Va plane
#define KPAD 416                    // padded K stride: rows = 832 B = 13 cache lines
                                    // (64B-aligned; payload 768 B = 12 full lines)
#define VPLANE_E ((size_t)MCOLS*KPAD)   // 1277952 elems per V plane
#define APLANE_E ((size_t)NI*KPAD)      // 159744 elems per A plane

typedef __attribute__((ext_vector_type(8))) short short8;
typedef __attribute__((ext_vector_type(4))) float floatx4;

struct alignas(8) US4 { unsigned short x, y, z, w; };

__device__ __forceinline__ float bf2f(unsigned short u){ return __uint_as_float(((unsigned)u) << 16); }
__device__ __forceinline__ unsigned short f2bf(float f){
    unsigned x = __float_as_uint(f);
    x += 0x7fffu + ((x >> 16) & 1u);          // round-to-nearest-even
    return (unsigned short)(x >> 16);
}

__device__ __forceinline__ float wave_sum(float v){
    #pragma unroll
    for (int m = 32; m > 0; m >>= 1) v += __shfl_xor(v, m, 64);
    return v;
}
__device__ __forceinline__ float wave_max(float v){
    #pragma unroll
    for (int m = 32; m > 0; m >>= 1) v = fmaxf(v, __shfl_xor(v, m, 64));
    return v;
}

// async global->LDS, 16B per lane; LDS dest is wave-uniform base + lane*16
__device__ __forceinline__ void gl_lds16(const unsigned short* g, unsigned short* l){
    __builtin_amdgcn_global_load_lds(
        (__attribute__((address_space(1))) void*)(g),
        (__attribute__((address_space(3))) void*)(l), 16, 0, 0);
}

// ---------------------------------------------------------------------------
// k_w: weight prep (unchanged from validated round-5 kernel).
// ---------------------------------------------------------------------------
__global__ __launch_bounds__(256) void k_w(
    const float* __restrict__ Wv, const float* __restrict__ Weg,
    const float* __restrict__ bV, const float* __restrict__ bEG,
    const float* __restrict__ Wo,
    unsigned short* __restrict__ WtA, unsigned short* __restrict__ WtB,
    float* __restrict__ bcoA, float* __restrict__ bcoB,
    unsigned short* __restrict__ WoT)
{
    const int t = threadIdx.x;
    for (int idx = t; idx < 5120; idx += 256){
        int n = idx >> 6, k = idx & 63;
        WtA[idx] = f2bf((n < 64) ? Wv[k*128 + n]      : Weg[k*32 + (n-64)]);
        WtB[idx] = f2bf((n < 64) ? Wv[k*128 + 64 + n] : Weg[k*32 + 16 + (n-64)]);
    }
    for (int idx = t; idx < 8192; idx += 256){
        int o = idx >> 7, c = idx & 127;
        int r = (c & 7)*16 + (c >> 3);
        WoT[idx] = f2bf(Wo[r*64 + o]);
    }
    if (t < 80){
        bcoA[t] = (t < 64) ? bV[t]      : bEG[t-64];
        bcoB[t] = (t < 64) ? bV[64 + t] : bEG[16 + t-64];
    }
}

// ---------------------------------------------------------------------------
// k_projsm: fused LayerNorm + [384,64]@[64,80] bf16 MFMA projection +
// in-block gated softmax. R14-validated data layout (f32 sg, KPAD=416) with
// ONE structural lever: 512 threads (8 waves), __launch_bounds__(512,4)
// -> 2 blocks/CU. Halves per-wave serial work per chunk (LN 1 pass, 10 MFMA,
// 1 epilogue m-frag, 1 softmax head) and REDUCES per-CU L2 block footprint
// 3->2 (R15 showed more co-resident blocks thrash L2). Waves/CU 12->16.
// ---------------------------------------------------------------------------
__global__ __launch_bounds__(512, 4) void k_projsm(
    const float* __restrict__ e, const float* __restrict__ lns, const float* __restrict__ lnb,
    const unsigned short* __restrict__ WtA, const unsigned short* __restrict__ WtB,
    const float* __restrict__ bcoA, const float* __restrict__ bcoB,
    const float* __restrict__ mask,
    unsigned short* __restrict__ VinP, unsigned short* __restrict__ VoutP,
    unsigned short* __restrict__ AinP, unsigned short* __restrict__ AoutP)
{
    __shared__ unsigned short Alds[128*64];   // 16 KB, XOR-swizzled chunks
    __shared__ unsigned short Wlds[80*64];    // 10 KB, XOR-swizzled chunks
    __shared__ float bcs[80];                 // 320 B
    __shared__ float sg[384][17];             // 26.1 KB  (total 53.1 KB)
    const int tid = threadIdx.x;
    const int y    = blockIdx.x;
    const int b    = blockIdx.y;
    const int pass = blockIdx.z;
    const int z8 = b * 8;

    const unsigned short* Wt = pass ? WtB : WtA;
    const float* bco         = pass ? bcoB : bcoA;
    unsigned short* Vdst     = pass ? VoutP : VinP;
    unsigned short* Adst     = pass ? AoutP : AinP;

    // stage weight slice into swizzled LDS [80][64]
    for (int c = tid; c < 640; c += 512){
        int n = c >> 3, pos = (c & 7) ^ (n & 7);
        short8 v = *(const short8*)&Wt[c*8];
        *(short8*)&Wlds[n*64 + pos*8] = v;
    }
    if (tid < 80) bcs[tid] = bco[tid];

    const int lq = tid & 3;
    float scv[16], bsv[16];
    #pragma unroll
    for (int j = 0; j < 4; ++j){
        float4 s4 = *(const float4*)&lns[lq*16 + j*4];
        float4 b4 = *(const float4*)&lnb[lq*16 + j*4];
        scv[j*4+0]=s4.x; scv[j*4+1]=s4.y; scv[j*4+2]=s4.z; scv[j*4+3]=s4.w;
        bsv[j*4+0]=b4.x; bsv[j*4+1]=b4.y; bsv[j*4+2]=b4.z; bsv[j*4+3]=b4.w;
    }

    const int w = tid >> 6, l = tid & 63;
    const int lr = l & 15, lk4 = l >> 4;
    const int rowoff = lk4 * 4;
    const int lrow = tid >> 2;                 // 0..127: one LN row per thread

    auto LOAD = [&](float (&xs)[16], int cx){
        size_t gbase;
        if (pass == 0) gbase = (((size_t)(b*NI + y)) * NI + cx*128 + lrow) * NE + lq*16;
        else           gbase = (((size_t)(b*NI + cx*128 + lrow)) * NI + y) * NE + lq*16;
        #pragma unroll
        for (int j = 0; j < 4; ++j){
            float4 x4 = *(const float4*)&e[gbase + j*4];
            xs[j*4+0]=x4.x; xs[j*4+1]=x4.y; xs[j*4+2]=x4.z; xs[j*4+3]=x4.w;
        }
    };

    auto LNWRITE = [&](const float (&xs)[16]){
        float s = 0.f, sq = 0.f;
        #pragma unroll
        for (int j = 0; j < 16; ++j){ s += xs[j]; sq += xs[j]*xs[j]; }
        s  += __shfl_xor(s, 1, 64);  s  += __shfl_xor(s, 2, 64);
        sq += __shfl_xor(sq, 1, 64); sq += __shfl_xor(sq, 2, 64);
        float mu = s * (1.f/64.f);
        float var = sq * (1.f/64.f) - mu*mu;
        float rs = rsqrtf(var + 1e-5f);
        short8 o0, o1;
        #pragma unroll
        for (int j = 0; j < 8; ++j){
            o0[j] = (short)f2bf((xs[j]   - mu)*rs*scv[j]   + bsv[j]);
            o1[j] = (short)f2bf((xs[j+8] - mu)*rs*scv[j+8] + bsv[j+8]);
        }
        const int sw = lrow & 7;
        *(short8*)&Alds[lrow*64 + ((lq*2    ) ^ sw)*8] = o0;
        *(short8*)&Alds[lrow*64 + ((lq*2 + 1) ^ sw)*8] = o1;
    };

    float xsA[16], xsB[16];
    LOAD(xsA, 0);

    #pragma unroll
    for (int cx = 0; cx < 3; ++cx){
        const int x0 = cx * 128;
        __syncthreads();   // Wlds staged (cx=0) / prev chunk's Alds reads done
        if (cx & 1) LNWRITE(xsB); else LNWRITE(xsA);
        __syncthreads();   // Alds ready
        if (cx == 0) LOAD(xsB, 1);           // prefetch: hides under MFMA+epilogue
        else if (cx == 1) LOAD(xsA, 2);

        // MFMA: wave w owns row-frag w (rows w*16..w*16+15) x 80 cols (5 frags)
        floatx4 acc[5];
        #pragma unroll
        for (int nf = 0; nf < 5; ++nf)
            acc[nf] = (floatx4){0.f,0.f,0.f,0.f};

        #pragma unroll
        for (int ks = 0; ks < 2; ++ks){
            const int ch = ((ks*4 + lk4) ^ (lr & 7)) * 8;
            short8 a0 = *(const short8*)&Alds[(w*16 + lr)*64 + ch];
            #pragma unroll
            for (int nf = 0; nf < 5; ++nf){
                short8 bfr = *(const short8*)&Wlds[(nf*16 + lr)*64 + ch];
                acc[nf] = __builtin_amdgcn_mfma_f32_16x16x32_bf16(a0, bfr, acc[nf], 0, 0, 0);
            }
        }

        // Epilogue: V columns -> coalesced global; S/G columns -> LDS sg
        {
            const int bl = x0 + w*16 + rowoff;
            #pragma unroll
            for (int nf = 0; nf < 4; ++nf){
                int ca = nf*16 + lr;
                int dd = ca >> 3, h = ca & 7;
                float bia = bcs[ca];
                US4 v;
                v.x = f2bf(acc[nf][0] + bia);
                v.y = f2bf(acc[nf][1] + bia);
                v.z = f2bf(acc[nf][2] + bia);
                v.w = f2bf(acc[nf][3] + bia);
                *(US4*)&Vdst[(size_t)(z8 + h)*VPLANE_E + (size_t)(y*8 + dd)*KPAD + bl] = v;
            }
            {
                float bia = bcs[64 + lr];
                #pragma unroll
                for (int q = 0; q < 4; ++q)
                    sg[bl + q][lr] = acc[4][q] + bia;
            }
        }
    }
    __syncthreads();

    // Softmax + gate over the block's 384-row axis; wave w owns head h = w
    float mv[6];
    if (pass == 0){
        #pragma unroll
        for (int q = 0; q < 6; ++q)
            mv[q] = mask[((size_t)b*NI + y)*NI + l + q*64];
    }
    {
        const int h = w;
        float sv[6], gv[6];
        float m = -1e30f;
        #pragma unroll
        for (int q = 0; q < 6; ++q){
            int j = l + q*64;
            float mk = (pass == 0) ? mv[q] : 0.f;
            sv[q] = sg[j][h]     + mk;
            gv[q] = sg[j][8 + h] + mk;
            m = fmaxf(m, sv[q]);
        }
        m = wave_max(m);
        float ssum = 0.f;
        #pragma unroll
        for (int q = 0; q < 6; ++q){ sv[q] = expf(sv[q] - m); ssum += sv[q]; }
        ssum = wave_sum(ssum);
        float inv = 1.f / ssum;
        unsigned short* dst = Adst + (size_t)(z8 + h)*APLANE_E + (size_t)y*KPAD;
        #pragma unroll
        for (int q = 0; q < 6; ++q){
            float sig = 1.f / (1.f + expf(-gv[q]));
            dst[l + q*64] = f2bf(sv[q] * inv * sig);
        }
    }
}

// ---------------------------------------------------------------------------
// k_gemm: C[384,3072] = A[384,384] @ B^T (B stored [n][k]), bf16 MFMA.
// (unchanged validated round-7 kernel: 0 bank conflicts)
// ---------------------------------------------------------------------------
__global__ __launch_bounds__(256, 2) void k_gemm(
    const unsigned short* __restrict__ AinP, const unsigned short* __restrict__ AoutP,
    const unsigned short* __restrict__ VinP, const unsigned short* __restrict__ VoutP,
    unsigned short* __restrict__ VaIn, unsigned short* __restrict__ VaOut)
{
    __shared__ unsigned short Al[128*64];    // 16 KB, linear [row][64], swizzled chunks
    __shared__ unsigned short Bl[256*64];    // 32 KB
    const int tid = threadIdx.x;

    // XCD-aware bijective swizzle: 1152 blocks = 8 XCDs x 144
    const int L = blockIdx.x;
    const int W = (L & 7) * 144 + (L >> 3);
    const int nt = W % 12;
    const int mt = (W / 12) % 3;
    const int z  = W / 36;
    const int dir = z >> 4, bh = z & 15;
    const unsigned short* Ap = (dir ? AoutP : AinP) + (size_t)bh * APLANE_E;
    const unsigned short* Bp = (dir ? VoutP : VinP) + (size_t)bh * VPLANE_E;
    unsigned short* Cp = (dir ? VaOut : VaIn) + (size_t)bh * PLANE;
    const int m0 = mt*128, n0 = nt*256;

    const int w = tid >> 6, l = tid & 63;
    const int lr = l & 15, lk4 = l >> 4;
    const int wr = w >> 1, wc = w & 1;

    // staging lane geometry: lane l covers (row_in_inst = l>>3, physical chunk = l&7)
    const int srow8  = l >> 3;                      // 0..7
    const int schunk = (l & 7) ^ (srow8 & 7);       // logical chunk to fetch

    floatx4 acc[4][8];
    #pragma unroll
    for (int mf = 0; mf < 4; ++mf)
        #pragma unroll
        for (int nf = 0; nf < 8; ++nf)
            acc[mf][nf] = (floatx4){0.f,0.f,0.f,0.f};

    for (int kb = 0; kb < 6; ++kb){
        const int k0 = kb*64;
        __syncthreads();                            // prev compute done before overwrite
        #pragma unroll
        for (int t = 0; t < 4; ++t){
            int inst = w*4 + t;
            gl_lds16(&Ap[(size_t)(m0 + inst*8 + srow8)*KPAD + k0 + schunk*8],
                     &Al[inst*512]);
        }
        #pragma unroll
        for (int t = 0; t < 8; ++t){
            int inst = w*8 + t;
            gl_lds16(&Bp[(size_t)(n0 + inst*8 + srow8)*KPAD + k0 + schunk*8],
                     &Bl[inst*512]);
        }
        asm volatile("s_waitcnt vmcnt(0)" ::: "memory");
        __syncthreads();
        #pragma unroll
        for (int ks = 0; ks < 2; ++ks){
            const int cx = ((ks*4 + lk4) ^ (lr & 7)) * 8;   // swizzled chunk offset (shorts)
            short8 a[4], b[8];
            #pragma unroll
            for (int mf = 0; mf < 4; ++mf)
                a[mf] = *(const short8*)&Al[(wr*64 + mf*16 + lr)*64 + cx];
            #pragma unroll
            for (int nf = 0; nf < 8; ++nf)
                b[nf] = *(const short8*)&Bl[(wc*128 + nf*16 + lr)*64 + cx];
            #pragma unroll
            for (int mf = 0; mf < 4; ++mf)
                #pragma unroll
                for (int nf = 0; nf < 8; ++nf)
                    acc[mf][nf] = __builtin_amdgcn_mfma_f32_16x16x32_bf16(a[mf], b[nf], acc[mf][nf], 0, 0, 0);
        }
    }

    const int rowoff = lk4 * 4;
    #pragma unroll
    for (int mf = 0; mf < 4; ++mf)
        #pragma unroll
        for (int q = 0; q < 4; ++q){
            int i = m0 + wr*64 + mf*16 + rowoff + q;
            #pragma unroll
            for (int nf = 0; nf < 8; ++nf){
                int n = n0 + wc*128 + nf*16 + lr;
                Cp[(size_t)i*MCOLS + n] = f2bf(acc[mf][nf][q]);
            }
        }
}

// ---------------------------------------------------------------------------
// k_f2: epilogue GEMM via MFMA, no A-staging.
// (unchanged from validated round-5 kernel)
// ---------------------------------------------------------------------------
__global__ __launch_bounds__(192) void k_f2(
    const unsigned short* __restrict__ Vain, const unsigned short* __restrict__ Vaout,
    const unsigned short* __restrict__ WoT, const float* __restrict__ bO,
    float* __restrict__ out)
{
    __shared__ unsigned short wl[64*136];
    const int tid = threadIdx.x;
    const int jt = blockIdx.x, i = blockIdx.y, b = blockIdx.z;

    for (int cc = tid; cc < 1024; cc += 192){     // stage WoT [64][128] -> [64][136]
        int o = cc >> 4, k8 = (cc & 15) * 8;
        short8 v = *(const short8*)&WoT[cc*8];
        *(short8*)&wl[o*136 + k8] = v;
    }

    const int w = tid >> 6, l = tid & 63;
    const int lr = l & 15, lk = (l >> 4) * 8;
    const int j0 = jt*192 + w*64;

    float bias[4];
    #pragma unroll
    for (int nf = 0; nf < 4; ++nf) bias[nf] = bO[nf*16 + lr];

    __syncthreads();

    short8 bfr[4][4];
    #pragma unroll
    for (int ks = 0; ks < 4; ++ks)
        #pragma unroll
        for (int nf = 0; nf < 4; ++nf)
            bfr[ks][nf] = *(const short8*)&wl[(nf*16 + lr)*136 + ks*32 + lk];

    floatx4 acc[4][4];
    #pragma unroll
    for (int mf = 0; mf < 4; ++mf)
        #pragma unroll
        for (int nf = 0; nf < 4; ++nf)
            acc[mf][nf] = (floatx4){0.f,0.f,0.f,0.f};

    const int p_lane = (l >> 4);
    #pragma unroll
    for (int mf = 0; mf < 4; ++mf){
        int j = j0 + mf*16 + lr;
        short8 a[4];
        #pragma unroll
        for (int ks = 0; ks < 4; ++ks){
            int p = ks*4 + p_lane;
            const unsigned short* src = (p >= 8) ? Vaout : Vain;
            int h = p & 7;
            a[ks] = *(const short8*)&src[(size_t)(b*8 + h)*PLANE + (size_t)i*MCOLS + (size_t)j*8];
        }
        #pragma unroll
        for (int ks = 0; ks < 4; ++ks)
            #pragma unroll
            for (int nf = 0; nf < 4; ++nf)
                acc[mf][nf] = __builtin_amdgcn_mfma_f32_16x16x32_bf16(a[ks], bfr[ks][nf], acc[mf][nf], 0, 0, 0);
    }

    const int rowoff = (l >> 4) * 4;
    const size_t obase = ((size_t)(b*NI + i)) * NI;
    #pragma unroll
    for (int mf = 0; mf < 4; ++mf)
        #pragma unroll
        for (int q = 0; q < 4; ++q){
            int j = j0 + mf*16 + rowoff + q;
            #pragma unroll
            for (int nf = 0; nf < 4; ++nf)
                out[(obase + j)*NE + nf*16 + lr] = acc[mf][nf][q] + bias[nf];
        }
}

// ---------------------------------------------------------------------------
extern "C" void kernel_launch(void* const* d_in, const int* in_sizes, int n_in,
                              void* d_out, int out_size, void* d_ws, size_t ws_size,
                              hipStream_t stream)
{
    const float* e    = (const float*)d_in[0];
    const float* mask = (const float*)d_in[1];
    const float* lns  = (const float*)d_in[2];
    const float* lnb  = (const float*)d_in[3];
    const float* Wv   = (const float*)d_in[4];
    const float* bV   = (const float*)d_in[5];
    const float* Weg  = (const float*)d_in[6];
    const float* bEG  = (const float*)d_in[7];
    const float* Wo   = (const float*)d_in[8];
    const float* bO   = (const float*)d_in[9];

    // ws layout (bytes): VinP/VoutP 2x40,894,464 (ends 81,788,928) |
    // AinP/AoutP 2x5,111,808 (ends 92,012,544) | weights ~37.5 KB (ends
    // 92,050,048) | VaIn+VaOut 2x37,748,736 (ends 167,547,520) < 188,743,680
    unsigned short* VinP  = (unsigned short*)d_ws;
    unsigned short* VoutP = VinP  + (size_t)16 * VPLANE_E;
    unsigned short* AinP  = VoutP + (size_t)16 * VPLANE_E;
    unsigned short* AoutP = AinP  + (size_t)16 * APLANE_E;
    unsigned short* WtA   = AoutP + (size_t)16 * APLANE_E;
    unsigned short* WtB   = WtA + 5120;
    unsigned short* WoT   = WtB + 5120;
    float* bcoA = (float*)(WoT + 8192);
    float* bcoB = bcoA + 80;
    unsigned short* VaIn  = (unsigned short*)(bcoB + 80);
    unsigned short* VaOut = VaIn + (size_t)16 * PLANE;

    k_w<<<1, 256, 0, stream>>>(Wv, Weg, bV, bEG, Wo, WtA, WtB, bcoA, bcoB, WoT);
    k_projsm<<<dim3(NI, NB, 2), 512, 0, stream>>>(e, lns, lnb, WtA, WtB, bcoA, bcoB,
                                                  mask, VinP, VoutP, AinP, AoutP);
    k_gemm<<<dim3(1152), 256, 0, stream>>>(AinP, AoutP, VinP, VoutP, VaIn, VaOut);
    k_f2  <<<dim3(2, NI, NB), 192, 0, stream>>>(VaIn, VaOut, WoT, bO, (float*)d_out);
}